// Round 11
// baseline (378.114 us; speedup 1.0000x reference)
//
#include <hip/hip_runtime.h>

// Problem constants (reference shape (64,1,480,640) fp32)
#define B_SAMPLES 64
#define F4PS      76800      // float4 per sample
#define BPS       30         // blocks per sample
#define NBLK      (B_SAMPLES * BPS)   // 1920
#define F4PB      2560       // float4 per block
#define TPB       256        // threads per block
#define ITERS     10         // F4PB / TPB
#define WPB       4          // waves per block
#define EPS_DET   1e-6f
#define SPIN_LIMIT (1 << 22) // termination insurance; not hit in practice

typedef __attribute__((address_space(3))) void       lds_void;
typedef const __attribute__((address_space(1))) void gbl_void;

__device__ __forceinline__ bool finitef(float x) {
    return (__float_as_uint(x) & 0x7f800000u) != 0x7f800000u;
}

// Local mask-layout detection: block scans 4 KiB of ITS OWN chunk.
// int32 0/1 => bytes at 4k+{1,2,3} all zero; byte-bool => ~50% of ~3072
// scanned high-bytes nonzero (P[miss] ~ 2^-3072).
__device__ __forceinline__ bool detect_byte_layout(const void* mask, int base4,
                                                   int* sflag) {
    const uint4* m16 =
        (const uint4*)((const unsigned char*)mask + (size_t)base4 * 4);
    uint4 m = m16[threadIdx.x];                     // 256 thr x 16 B = 4 KiB
    unsigned v = (m.x | m.y | m.z | m.w) & 0xffffff00u;
    if (threadIdx.x == 0) *sflag = 0;
    __syncthreads();
    if (__any(v != 0) && (threadIdx.x & 63) == 0) *sflag = 1;
    __syncthreads();
    return *sflag != 0;
}

// async stage: p 1KB + t 1KB + mask 256B per wave-tile -> LDS
__device__ __forceinline__ void stage3(const float4* gp, const float4* gt,
                                       const unsigned* gm, unsigned char* lbuf) {
    __builtin_amdgcn_global_load_lds((gbl_void*)gp, (lds_void*)lbuf, 16, 0, 0);
    __builtin_amdgcn_global_load_lds((gbl_void*)gt, (lds_void*)(lbuf + 1024), 16, 0, 0);
    __builtin_amdgcn_global_load_lds((gbl_void*)gm, (lds_void*)(lbuf + 2048), 4, 0, 0);
}

// ===========================================================================
// Lean fused kernel: pass1 sums (R6 body) -> per-sample release/acquire sync
// (all 1920 blocks co-resident at ~19KB LDS / 48 VGPR -> 8 blocks/CU, 2048
// slots) -> solve -> pass2 residual (R6 body, re-stages p,t,m). No LDS
// retention (R10 lesson), no embedded final (R5/R7 lesson).
// ===========================================================================
__global__ void
fused(const float* __restrict__ pred, const float* __restrict__ target,
      const void* __restrict__ mask, int* __restrict__ cnt,
      float* __restrict__ partials, float* __restrict__ rpart) {
    const int s   = blockIdx.x / BPS;
    const int sub = blockIdx.x % BPS;
    const int base4 = s * F4PS + sub * F4PB;
    const int tid = threadIdx.x, lane = tid & 63, w = tid >> 6;

    __shared__ __align__(16) unsigned char stg[WPB][2][2304];  // 18.4 KB
    __shared__ float red[WPB][5];
    __shared__ float s_ab[2];
    __shared__ int sflag;
    __shared__ int s_to;

    const bool byteLayout = detect_byte_layout(mask, base4, &sflag);
    const float4* p4 = (const float4*)pred;
    const float4* t4 = (const float4*)target;
    const unsigned* m4b = (const unsigned*)mask;

    unsigned char* buf0 = &stg[w][0][0];     // wave-uniform
    unsigned char* buf1 = &stg[w][1][0];
    const int i0 = base4 + w * 64 + lane;

    // ---------------- pass 1: masked sums (R6 body) ----------------
    float n = 0.f, sp = 0.f, st = 0.f, sp2 = 0.f, spt = 0.f;
    auto acc1 = [&](float p, float t, bool ok) {
        float pv = ok ? p : 0.f;
        float tv = ok ? t : 0.f;
        n += ok ? 1.f : 0.f;
        sp += pv; st += tv; sp2 += pv * pv; spt += pv * tv;
    };

    if (byteLayout) {
        stage3(p4 + i0, t4 + i0, m4b + i0, buf0);
#pragma unroll
        for (int t = 0; t < ITERS; ++t) {
            unsigned char* cur = (t & 1) ? buf1 : buf0;
            unsigned char* nxt = (t & 1) ? buf0 : buf1;
            if (t < ITERS - 1) {
                const int i4 = i0 + (t + 1) * TPB;
                stage3(p4 + i4, t4 + i4, m4b + i4, nxt);
                __builtin_amdgcn_sched_barrier(0);
                asm volatile("s_waitcnt vmcnt(3)" ::: "memory");
            } else {
                __builtin_amdgcn_sched_barrier(0);
                asm volatile("s_waitcnt vmcnt(0)" ::: "memory");
            }
            __builtin_amdgcn_sched_barrier(0);
            const float4  pv = *(const float4*)(cur + (size_t)lane * 16);
            const float4  tv = *(const float4*)(cur + 1024 + (size_t)lane * 16);
            const unsigned mm = *(const unsigned*)(cur + 2048 + (size_t)lane * 4);
            acc1(pv.x, tv.x, (mm & 0x000000ffu) && finitef(pv.x) && finitef(tv.x));
            acc1(pv.y, tv.y, (mm & 0x0000ff00u) && finitef(pv.y) && finitef(tv.y));
            acc1(pv.z, tv.z, (mm & 0x00ff0000u) && finitef(pv.z) && finitef(tv.z));
            acc1(pv.w, tv.w, (mm & 0xff000000u) && finitef(pv.w) && finitef(tv.w));
        }
    } else {
        const int4* m4 = (const int4*)mask;
        for (int t = 0; t < ITERS; ++t) {
            const int i4 = base4 + t * TPB + tid;
            float4 p = p4[i4]; float4 tt = t4[i4]; int4 mm = m4[i4];
            acc1(p.x, tt.x, mm.x && finitef(p.x) && finitef(tt.x));
            acc1(p.y, tt.y, mm.y && finitef(p.y) && finitef(tt.y));
            acc1(p.z, tt.z, mm.z && finitef(p.z) && finitef(tt.z));
            acc1(p.w, tt.w, mm.w && finitef(p.w) && finitef(tt.w));
        }
    }

    // block reduce 5 quantities -> partials (release stores)
    {
        float vals[5] = {n, sp, st, sp2, spt};
#pragma unroll
        for (int q = 0; q < 5; ++q) {
            float v = vals[q];
#pragma unroll
            for (int off = 32; off; off >>= 1) v += __shfl_xor(v, off);
            if (lane == 0) red[w][q] = v;
        }
        __syncthreads();
        if (tid == 0) {
#pragma unroll
            for (int q = 0; q < 5; ++q)
                __hip_atomic_store(&partials[(size_t)blockIdx.x * 5 + q],
                                   red[0][q] + red[1][q] + red[2][q] + red[3][q],
                                   __ATOMIC_RELEASE, __HIP_MEMORY_SCOPE_AGENT);
        }
    }

    // ---------------- per-sample sync (30 blocks) ----------------
    if (tid == 0) {
        __threadfence();
        atomicAdd(&cnt[s], 1);
        int it = 0;
        while (__hip_atomic_load(&cnt[s], __ATOMIC_ACQUIRE,
                                 __HIP_MEMORY_SCOPE_AGENT) < BPS &&
               it < SPIN_LIMIT) {
            __builtin_amdgcn_s_sleep(2);
            ++it;
        }
        s_to = (it >= SPIN_LIMIT) ? 1 : 0;
    }
    __syncthreads();

    // ---------------- solve (a,b) ----------------
    if (!s_to) {
        if (tid < 64) {
            float q0 = 0.f, q1 = 0.f, q2 = 0.f, q3 = 0.f, q4 = 0.f;
            if (tid < BPS) {
                const float* q = partials + (size_t)(s * BPS + tid) * 5;
                q0 = __hip_atomic_load(q + 0, __ATOMIC_ACQUIRE, __HIP_MEMORY_SCOPE_AGENT);
                q1 = __hip_atomic_load(q + 1, __ATOMIC_ACQUIRE, __HIP_MEMORY_SCOPE_AGENT);
                q2 = __hip_atomic_load(q + 2, __ATOMIC_ACQUIRE, __HIP_MEMORY_SCOPE_AGENT);
                q3 = __hip_atomic_load(q + 3, __ATOMIC_ACQUIRE, __HIP_MEMORY_SCOPE_AGENT);
                q4 = __hip_atomic_load(q + 4, __ATOMIC_ACQUIRE, __HIP_MEMORY_SCOPE_AGENT);
            }
#pragma unroll
            for (int off = 32; off; off >>= 1) {
                q0 += __shfl_xor(q0, off); q1 += __shfl_xor(q1, off);
                q2 += __shfl_xor(q2, off); q3 += __shfl_xor(q3, off);
                q4 += __shfl_xor(q4, off);
            }
            if (tid == 0) {
                float det = q0 * q3 - q1 * q1;
                bool safe = fabsf(det) > EPS_DET;
                float a  = safe ? (q0 * q4 - q1 * q2) / det : 1.f;
                float bb = safe ? (q2 - a * q1) / fmaxf(q0, 1.f) : 0.f;
                s_ab[0] = a; s_ab[1] = bb;
            }
        }
    } else {
        // termination insurance: recompute this sample's full sums directly
        float fn = 0.f, fsp = 0.f, fst = 0.f, fsp2 = 0.f, fspt = 0.f;
        for (int i = s * F4PS + tid; i < (s + 1) * F4PS; i += TPB) {
            float4 p = p4[i]; float4 tt = t4[i];
            bool o0, o1, o2, o3;
            if (byteLayout) {
                unsigned mm = m4b[i];
                o0 = (mm & 0x000000ffu) && finitef(p.x) && finitef(tt.x);
                o1 = (mm & 0x0000ff00u) && finitef(p.y) && finitef(tt.y);
                o2 = (mm & 0x00ff0000u) && finitef(p.z) && finitef(tt.z);
                o3 = (mm & 0xff000000u) && finitef(p.w) && finitef(tt.w);
            } else {
                int4 mm = ((const int4*)mask)[i];
                o0 = mm.x && finitef(p.x) && finitef(tt.x);
                o1 = mm.y && finitef(p.y) && finitef(tt.y);
                o2 = mm.z && finitef(p.z) && finitef(tt.z);
                o3 = mm.w && finitef(p.w) && finitef(tt.w);
            }
            fn += (o0 ? 1.f : 0.f) + (o1 ? 1.f : 0.f) + (o2 ? 1.f : 0.f) + (o3 ? 1.f : 0.f);
            float px = o0 ? p.x : 0.f, py = o1 ? p.y : 0.f, pz = o2 ? p.z : 0.f, pw = o3 ? p.w : 0.f;
            float tx = o0 ? tt.x : 0.f, ty = o1 ? tt.y : 0.f, tz = o2 ? tt.z : 0.f, tw = o3 ? tt.w : 0.f;
            fsp += px + py + pz + pw;
            fst += tx + ty + tz + tw;
            fsp2 += px * px + py * py + pz * pz + pw * pw;
            fspt += px * tx + py * ty + pz * tz + pw * tw;
        }
        float vals[5] = {fn, fsp, fst, fsp2, fspt};
#pragma unroll
        for (int q = 0; q < 5; ++q) {
            float v = vals[q];
#pragma unroll
            for (int off = 32; off; off >>= 1) v += __shfl_xor(v, off);
            if (lane == 0) red[w][q] = v;
        }
        __syncthreads();
        if (tid == 0) {
            float q0 = red[0][0] + red[1][0] + red[2][0] + red[3][0];
            float q1 = red[0][1] + red[1][1] + red[2][1] + red[3][1];
            float q2 = red[0][2] + red[1][2] + red[2][2] + red[3][2];
            float q3 = red[0][3] + red[1][3] + red[2][3] + red[3][3];
            float q4 = red[0][4] + red[1][4] + red[2][4] + red[3][4];
            float det = q0 * q3 - q1 * q1;
            bool safe = fabsf(det) > EPS_DET;
            float a  = safe ? (q0 * q4 - q1 * q2) / det : 1.f;
            float bb = safe ? (q2 - a * q1) / fmaxf(q0, 1.f) : 0.f;
            s_ab[0] = a; s_ab[1] = bb;
        }
    }
    __syncthreads();
    const float av = s_ab[0];
    const float bv = s_ab[1];

    // ---------------- pass 2: residual (R6 body) ----------------
    float r = 0.f;
    auto racc = [&](float p, float t, bool ok) {
        r += ok ? fabsf(av * p + bv - t) : 0.f;
    };

    if (byteLayout) {
        stage3(p4 + i0, t4 + i0, m4b + i0, buf0);
#pragma unroll
        for (int t = 0; t < ITERS; ++t) {
            unsigned char* cur = (t & 1) ? buf1 : buf0;
            unsigned char* nxt = (t & 1) ? buf0 : buf1;
            if (t < ITERS - 1) {
                const int i4 = i0 + (t + 1) * TPB;
                stage3(p4 + i4, t4 + i4, m4b + i4, nxt);
                __builtin_amdgcn_sched_barrier(0);
                asm volatile("s_waitcnt vmcnt(3)" ::: "memory");
            } else {
                __builtin_amdgcn_sched_barrier(0);
                asm volatile("s_waitcnt vmcnt(0)" ::: "memory");
            }
            __builtin_amdgcn_sched_barrier(0);
            const float4  pv = *(const float4*)(cur + (size_t)lane * 16);
            const float4  tv = *(const float4*)(cur + 1024 + (size_t)lane * 16);
            const unsigned mm = *(const unsigned*)(cur + 2048 + (size_t)lane * 4);
            racc(pv.x, tv.x, (mm & 0x000000ffu) && finitef(pv.x) && finitef(tv.x));
            racc(pv.y, tv.y, (mm & 0x0000ff00u) && finitef(pv.y) && finitef(tv.y));
            racc(pv.z, tv.z, (mm & 0x00ff0000u) && finitef(pv.z) && finitef(tv.z));
            racc(pv.w, tv.w, (mm & 0xff000000u) && finitef(pv.w) && finitef(tv.w));
        }
    } else {
        const int4* m4 = (const int4*)mask;
        for (int t = 0; t < ITERS; ++t) {
            const int i4 = base4 + t * TPB + tid;
            float4 p = p4[i4]; float4 tt = t4[i4]; int4 mm = m4[i4];
            racc(p.x, tt.x, mm.x && finitef(p.x) && finitef(tt.x));
            racc(p.y, tt.y, mm.y && finitef(p.y) && finitef(tt.y));
            racc(p.z, tt.z, mm.z && finitef(p.z) && finitef(tt.z));
            racc(p.w, tt.w, mm.w && finitef(p.w) && finitef(tt.w));
        }
    }

    {
        float v = r;
#pragma unroll
        for (int off = 32; off; off >>= 1) v += __shfl_xor(v, off);
        if (lane == 0) red[w][0] = v;
        __syncthreads();
        if (tid == 0)
            rpart[blockIdx.x] = red[0][0] + red[1][0] + red[2][0] + red[3][0];
    }
}

// Final loss. One wave, thread s = sample s.
__global__ void final_kernel(const float* __restrict__ partials,
                             const float* __restrict__ rpart,
                             float* __restrict__ out) {
    const int s = threadIdx.x;  // 64 threads = 1 wave
    double r = 0, n = 0;
    for (int b = 0; b < BPS; ++b) {
        r += (double)rpart[s * BPS + b];
        n += (double)partials[(size_t)(s * BPS + b) * 5 + 0];
    }
    double per = r / fmax(n, 1.0);
    double inc = (n >= 2.0) ? 1.0 : 0.0;
    double v = per * inc;
#pragma unroll
    for (int off = 32; off; off >>= 1) {
        v += __shfl_down(v, off);
        inc += __shfl_down(inc, off);
    }
    if (s == 0) out[0] = (float)(inc > 0.0 ? v / fmax(inc, 1.0) : 0.0);
}

extern "C" void kernel_launch(void* const* d_in, const int* in_sizes, int n_in,
                              void* d_out, int out_size, void* d_ws, size_t ws_size,
                              hipStream_t stream) {
    const float* pred = (const float*)d_in[0];
    const float* target = (const float*)d_in[1];
    const void* mask = d_in[2];
    float* out = (float*)d_out;

    // workspace layout
    int* cnt = (int*)d_ws;                                   // 64 ints
    float* partials = (float*)((char*)d_ws + 512);           // 1920*5 fp32
    float* rpart = partials + (size_t)NBLK * 5;              // 1920 fp32

    // per-sample counters MUST be zero at the start of every call
    hipMemsetAsync(cnt, 0, 256, stream);

    fused<<<NBLK, TPB, 0, stream>>>(pred, target, mask, cnt, partials, rpart);
    final_kernel<<<1, 64, 0, stream>>>(partials, rpart, out);
}

// Round 12
// 80.348 us; speedup vs baseline: 4.7059x; 4.7059x over previous
//
#include <hip/hip_runtime.h>

// Problem constants (reference shape (64,1,480,640) fp32)
#define B_SAMPLES 64
#define F4PS      76800      // float4 per sample
#define BPS       30         // blocks per sample
#define NBLK      (B_SAMPLES * BPS)   // 1920
#define F4PB      2560       // float4 per block
#define TPB       256        // threads per block
#define ITERS     10         // F4PB / TPB
#define WPB       4          // waves per block
#define EPS_DET   1e-6f
#define BM_DW     320        // bit-mask dwords per block (1280 B)

typedef __attribute__((address_space(3))) void       lds_void;
typedef const __attribute__((address_space(1))) void gbl_void;

__device__ __forceinline__ bool finitef(float x) {
    return (__float_as_uint(x) & 0x7f800000u) != 0x7f800000u;
}

// Local mask-layout detection (pass 1 only): block scans 4 KiB of own chunk.
__device__ __forceinline__ bool detect_byte_layout(const void* mask, int base4,
                                                   int* sflag) {
    const uint4* m16 =
        (const uint4*)((const unsigned char*)mask + (size_t)base4 * 4);
    uint4 m = m16[threadIdx.x];                     // 256 thr x 16 B = 4 KiB
    unsigned v = (m.x | m.y | m.z | m.w) & 0xffffff00u;
    if (threadIdx.x == 0) *sflag = 0;
    __syncthreads();
    if (__any(v != 0) && (threadIdx.x & 63) == 0) *sflag = 1;
    __syncthreads();
    return *sflag != 0;
}

__device__ __forceinline__ void stage3(const float4* gp, const float4* gt,
                                       const unsigned* gm, unsigned char* lbuf) {
    __builtin_amdgcn_global_load_lds((gbl_void*)gp, (lds_void*)lbuf, 16, 0, 0);
    __builtin_amdgcn_global_load_lds((gbl_void*)gt, (lds_void*)(lbuf + 1024), 16, 0, 0);
    __builtin_amdgcn_global_load_lds((gbl_void*)gm, (lds_void*)(lbuf + 2048), 4, 0, 0);
}
__device__ __forceinline__ void stage2(const float4* gp, const float4* gt,
                                       unsigned char* lbuf) {
    __builtin_amdgcn_global_load_lds((gbl_void*)gp, (lds_void*)lbuf, 16, 0, 0);
    __builtin_amdgcn_global_load_lds((gbl_void*)gt, (lds_void*)(lbuf + 1024), 16, 0, 0);
}

// ---------------------------------------------------------------------------
// Kernel 1: masked partial sums + packed validity bits (BITPK).
// R6 body verbatim + ballot emit. No ticket, no final embed.
// ---------------------------------------------------------------------------
template <bool BITPK>
__global__ void
sums_kernel(const float* __restrict__ pred, const float* __restrict__ target,
            const void* __restrict__ mask, float* __restrict__ partials,
            unsigned* __restrict__ bitpack) {
    const int s   = blockIdx.x / BPS;
    const int sub = blockIdx.x % BPS;
    const int base4 = s * F4PS + sub * F4PB;
    const int tid = threadIdx.x, lane = tid & 63, w = tid >> 6;

    __shared__ __align__(16) unsigned char stg[WPB][2][2304];
    __shared__ unsigned long long bm64[WPB * ITERS * 4];    // 1280 B
    __shared__ float red[WPB][5];
    __shared__ int sflag;

    const bool byteLayout = detect_byte_layout(mask, base4, &sflag);
    const float4* p4 = (const float4*)pred;
    const float4* t4 = (const float4*)target;

    float n = 0.f, sp = 0.f, st = 0.f, sp2 = 0.f, spt = 0.f;
    auto acc1 = [&](float p, float t, bool ok) {
        float pv = ok ? p : 0.f;
        float tv = ok ? t : 0.f;
        n += ok ? 1.f : 0.f;
        sp += pv; st += tv; sp2 += pv * pv; spt += pv * tv;
    };
    auto emit = [&](int t, bool o0, bool o1, bool o2, bool o3) {
        if (BITPK) {
            unsigned long long B0 = __ballot(o0), B1 = __ballot(o1);
            unsigned long long B2 = __ballot(o2), B3 = __ballot(o3);
            if (lane == 0) {
                const int c = (w * ITERS + t) * 4;
                bm64[c] = B0; bm64[c + 1] = B1; bm64[c + 2] = B2; bm64[c + 3] = B3;
            }
        }
    };

    if (byteLayout) {
        const unsigned* m4 = (const unsigned*)mask;
        unsigned char* buf0 = &stg[w][0][0];
        unsigned char* buf1 = &stg[w][1][0];
        const int i0 = base4 + w * 64 + lane;
        stage3(p4 + i0, t4 + i0, m4 + i0, buf0);
#pragma unroll
        for (int t = 0; t < ITERS; ++t) {
            unsigned char* cur = (t & 1) ? buf1 : buf0;
            unsigned char* nxt = (t & 1) ? buf0 : buf1;
            if (t < ITERS - 1) {
                const int i4 = i0 + (t + 1) * TPB;
                stage3(p4 + i4, t4 + i4, m4 + i4, nxt);
                __builtin_amdgcn_sched_barrier(0);
                asm volatile("s_waitcnt vmcnt(3)" ::: "memory");
            } else {
                __builtin_amdgcn_sched_barrier(0);
                asm volatile("s_waitcnt vmcnt(0)" ::: "memory");
            }
            __builtin_amdgcn_sched_barrier(0);
            const float4  pv = *(const float4*)(cur + (size_t)lane * 16);
            const float4  tv = *(const float4*)(cur + 1024 + (size_t)lane * 16);
            const unsigned mm = *(const unsigned*)(cur + 2048 + (size_t)lane * 4);
            bool o0 = (mm & 0x000000ffu) && finitef(pv.x) && finitef(tv.x);
            bool o1 = (mm & 0x0000ff00u) && finitef(pv.y) && finitef(tv.y);
            bool o2 = (mm & 0x00ff0000u) && finitef(pv.z) && finitef(tv.z);
            bool o3 = (mm & 0xff000000u) && finitef(pv.w) && finitef(tv.w);
            emit(t, o0, o1, o2, o3);
            acc1(pv.x, tv.x, o0); acc1(pv.y, tv.y, o1);
            acc1(pv.z, tv.z, o2); acc1(pv.w, tv.w, o3);
        }
    } else {
        const int4* m4 = (const int4*)mask;
        for (int t = 0; t < ITERS; ++t) {
            // (wave w, lane) slot layout matches the bit layout used below
            const int i4 = base4 + w * 64 + lane + t * TPB;
            float4 p = p4[i4]; float4 tt = t4[i4]; int4 mm = m4[i4];
            bool o0 = mm.x && finitef(p.x) && finitef(tt.x);
            bool o1 = mm.y && finitef(p.y) && finitef(tt.y);
            bool o2 = mm.z && finitef(p.z) && finitef(tt.z);
            bool o3 = mm.w && finitef(p.w) && finitef(tt.w);
            emit(t, o0, o1, o2, o3);
            acc1(p.x, tt.x, o0); acc1(p.y, tt.y, o1);
            acc1(p.z, tt.z, o2); acc1(p.w, tt.w, o3);
        }
    }

    {
        float vals[5] = {n, sp, st, sp2, spt};
#pragma unroll
        for (int q = 0; q < 5; ++q) {
            float v = vals[q];
#pragma unroll
            for (int off = 32; off; off >>= 1) v += __shfl_xor(v, off);
            if (lane == 0) red[w][q] = v;
        }
        __syncthreads();   // also publishes bm64 block-wide
        if (tid == 0) {
#pragma unroll
            for (int q = 0; q < 5; ++q)
                partials[(size_t)blockIdx.x * 5 + q] =
                    red[0][q] + red[1][q] + red[2][q] + red[3][q];
        }
    }
    if (BITPK) {
        const unsigned* bm32 = (const unsigned*)bm64;
        unsigned* g = bitpack + (size_t)blockIdx.x * BM_DW;
        g[tid] = bm32[tid];
        if (tid < BM_DW - TPB) g[TPB + tid] = bm32[TPB + tid];
    }
}

// ---------------------------------------------------------------------------
// Kernel 2 (bitpack): solve + residual. Layout-independent: no mask reads,
// no detect. Stages only p,t (vmcnt(2)); validity bits from LDS.
// ---------------------------------------------------------------------------
__global__ void
resid_bits_kernel(const float* __restrict__ pred,
                  const float* __restrict__ target,
                  const float* __restrict__ partials,
                  const unsigned* __restrict__ bitpack,
                  float* __restrict__ rpart) {
    const int s   = blockIdx.x / BPS;
    const int sub = blockIdx.x % BPS;
    const int base4 = s * F4PS + sub * F4PB;
    const int tid = threadIdx.x, lane = tid & 63, w = tid >> 6;

    __shared__ __align__(16) unsigned char stg[WPB][2][2304];
    __shared__ unsigned long long bml64[WPB * ITERS * 4];   // 1280 B
    __shared__ float red[WPB];
    __shared__ float s_ab[2];

    const float4* p4 = (const float4*)pred;
    const float4* t4 = (const float4*)target;

    unsigned char* buf0 = &stg[w][0][0];
    unsigned char* buf1 = &stg[w][1][0];
    const int i0 = base4 + w * 64 + lane;
    stage2(p4 + i0, t4 + i0, buf0);                 // prefetch tile 0 early

    {   // load this block's validity bits (coalesced) into LDS
        unsigned* b32 = (unsigned*)bml64;
        b32[tid] = bitpack[(size_t)blockIdx.x * BM_DW + tid];
        if (tid < BM_DW - TPB)
            b32[TPB + tid] = bitpack[(size_t)blockIdx.x * BM_DW + TPB + tid];
    }

    // wave 0: gather sample's 30 partial rows, butterfly, lane 0 solves
    if (tid < 64) {
        float q0 = 0.f, q1 = 0.f, q2 = 0.f, q3 = 0.f, q4 = 0.f;
        if (tid < BPS) {
            const float* q = partials + (size_t)(s * BPS + tid) * 5;
            q0 = q[0]; q1 = q[1]; q2 = q[2]; q3 = q[3]; q4 = q[4];
        }
#pragma unroll
        for (int off = 32; off; off >>= 1) {
            q0 += __shfl_xor(q0, off); q1 += __shfl_xor(q1, off);
            q2 += __shfl_xor(q2, off); q3 += __shfl_xor(q3, off);
            q4 += __shfl_xor(q4, off);
        }
        if (tid == 0) {
            float det = q0 * q3 - q1 * q1;
            bool safe = fabsf(det) > EPS_DET;
            float a  = safe ? (q0 * q4 - q1 * q2) / det : 1.f;
            float bb = safe ? (q2 - a * q1) / fmaxf(q0, 1.f) : 0.f;
            s_ab[0] = a; s_ab[1] = bb;
        }
    }
    __syncthreads();   // publishes bits + a,b; drains prologue vmem (benign)
    const float av = s_ab[0];
    const float bv = s_ab[1];

    float r = 0.f;
#pragma unroll
    for (int t = 0; t < ITERS; ++t) {
        unsigned char* cur = (t & 1) ? buf1 : buf0;
        unsigned char* nxt = (t & 1) ? buf0 : buf1;
        if (t < ITERS - 1) {
            const int i4 = i0 + (t + 1) * TPB;
            stage2(p4 + i4, t4 + i4, nxt);
            __builtin_amdgcn_sched_barrier(0);
            asm volatile("s_waitcnt vmcnt(2)" ::: "memory");
        } else {
            __builtin_amdgcn_sched_barrier(0);
            asm volatile("s_waitcnt vmcnt(0)" ::: "memory");
        }
        __builtin_amdgcn_sched_barrier(0);
        const float4 pv = *(const float4*)(cur + (size_t)lane * 16);
        const float4 tv = *(const float4*)(cur + 1024 + (size_t)lane * 16);
        const int c = (w * ITERS + t) * 4;
        const unsigned long long B0 = bml64[c],     B1 = bml64[c + 1];
        const unsigned long long B2 = bml64[c + 2], B3 = bml64[c + 3];
        r += ((B0 >> lane) & 1ull) ? fabsf(av * pv.x + bv - tv.x) : 0.f;
        r += ((B1 >> lane) & 1ull) ? fabsf(av * pv.y + bv - tv.y) : 0.f;
        r += ((B2 >> lane) & 1ull) ? fabsf(av * pv.z + bv - tv.z) : 0.f;
        r += ((B3 >> lane) & 1ull) ? fabsf(av * pv.w + bv - tv.w) : 0.f;
    }

    {
        float v = r;
#pragma unroll
        for (int off = 32; off; off >>= 1) v += __shfl_xor(v, off);
        if (lane == 0) red[w] = v;
        __syncthreads();
        if (tid == 0)
            rpart[blockIdx.x] = red[0] + red[1] + red[2] + red[3];
    }
}

// ---------------------------------------------------------------------------
// Fallback resid (no bitpack; R6 path, mask re-read + detect)
// ---------------------------------------------------------------------------
__global__ void
resid_kernel(const float* __restrict__ pred, const float* __restrict__ target,
             const void* __restrict__ mask, const float* __restrict__ partials,
             float* __restrict__ rpart) {
    const int s   = blockIdx.x / BPS;
    const int sub = blockIdx.x % BPS;
    const int base4 = s * F4PS + sub * F4PB;
    const int tid = threadIdx.x, lane = tid & 63, w = tid >> 6;

    __shared__ __align__(16) unsigned char stg[WPB][2][2304];
    __shared__ float red[WPB];
    __shared__ float s_ab[2];
    __shared__ int sflag;

    const bool byteLayout = detect_byte_layout(mask, base4, &sflag);
    const float4* p4 = (const float4*)pred;
    const float4* t4 = (const float4*)target;
    const unsigned* m4b = (const unsigned*)mask;

    unsigned char* buf0 = &stg[w][0][0];
    unsigned char* buf1 = &stg[w][1][0];
    const int i0 = base4 + w * 64 + lane;
    if (byteLayout) stage3(p4 + i0, t4 + i0, m4b + i0, buf0);

    if (tid < 64) {
        float q0 = 0.f, q1 = 0.f, q2 = 0.f, q3 = 0.f, q4 = 0.f;
        if (tid < BPS) {
            const float* q = partials + (size_t)(s * BPS + tid) * 5;
            q0 = q[0]; q1 = q[1]; q2 = q[2]; q3 = q[3]; q4 = q[4];
        }
#pragma unroll
        for (int off = 32; off; off >>= 1) {
            q0 += __shfl_xor(q0, off); q1 += __shfl_xor(q1, off);
            q2 += __shfl_xor(q2, off); q3 += __shfl_xor(q3, off);
            q4 += __shfl_xor(q4, off);
        }
        if (tid == 0) {
            float det = q0 * q3 - q1 * q1;
            bool safe = fabsf(det) > EPS_DET;
            float a  = safe ? (q0 * q4 - q1 * q2) / det : 1.f;
            float bb = safe ? (q2 - a * q1) / fmaxf(q0, 1.f) : 0.f;
            s_ab[0] = a; s_ab[1] = bb;
        }
    }
    __syncthreads();
    const float av = s_ab[0];
    const float bv = s_ab[1];

    float r = 0.f;
    auto racc = [&](float p, float t, bool ok) {
        r += ok ? fabsf(av * p + bv - t) : 0.f;
    };

    if (byteLayout) {
#pragma unroll
        for (int t = 0; t < ITERS; ++t) {
            unsigned char* cur = (t & 1) ? buf1 : buf0;
            unsigned char* nxt = (t & 1) ? buf0 : buf1;
            if (t < ITERS - 1) {
                const int i4 = i0 + (t + 1) * TPB;
                stage3(p4 + i4, t4 + i4, m4b + i4, nxt);
                __builtin_amdgcn_sched_barrier(0);
                asm volatile("s_waitcnt vmcnt(3)" ::: "memory");
            } else {
                __builtin_amdgcn_sched_barrier(0);
                asm volatile("s_waitcnt vmcnt(0)" ::: "memory");
            }
            __builtin_amdgcn_sched_barrier(0);
            const float4  pv = *(const float4*)(cur + (size_t)lane * 16);
            const float4  tv = *(const float4*)(cur + 1024 + (size_t)lane * 16);
            const unsigned mm = *(const unsigned*)(cur + 2048 + (size_t)lane * 4);
            racc(pv.x, tv.x, (mm & 0x000000ffu) && finitef(pv.x) && finitef(tv.x));
            racc(pv.y, tv.y, (mm & 0x0000ff00u) && finitef(pv.y) && finitef(tv.y));
            racc(pv.z, tv.z, (mm & 0x00ff0000u) && finitef(pv.z) && finitef(tv.z));
            racc(pv.w, tv.w, (mm & 0xff000000u) && finitef(pv.w) && finitef(tv.w));
        }
    } else {
        const int4* m4 = (const int4*)mask;
        for (int t = 0; t < ITERS; ++t) {
            const int i4 = base4 + t * TPB + tid;
            float4 p = p4[i4]; float4 tt = t4[i4]; int4 mm = m4[i4];
            racc(p.x, tt.x, mm.x && finitef(p.x) && finitef(tt.x));
            racc(p.y, tt.y, mm.y && finitef(p.y) && finitef(tt.y));
            racc(p.z, tt.z, mm.z && finitef(p.z) && finitef(tt.z));
            racc(p.w, tt.w, mm.w && finitef(p.w) && finitef(tt.w));
        }
    }

    {
        float v = r;
#pragma unroll
        for (int off = 32; off; off >>= 1) v += __shfl_xor(v, off);
        if (lane == 0) red[w] = v;
        __syncthreads();
        if (tid == 0)
            rpart[blockIdx.x] = red[0] + red[1] + red[2] + red[3];
    }
}

// Final loss. One wave, thread s = sample s.
__global__ void final_kernel(const float* __restrict__ partials,
                             const float* __restrict__ rpart,
                             float* __restrict__ out) {
    const int s = threadIdx.x;  // 64 threads = 1 wave
    double r = 0, n = 0;
    for (int b = 0; b < BPS; ++b) {
        r += (double)rpart[s * BPS + b];
        n += (double)partials[(size_t)(s * BPS + b) * 5 + 0];
    }
    double per = r / fmax(n, 1.0);
    double inc = (n >= 2.0) ? 1.0 : 0.0;
    double v = per * inc;
#pragma unroll
    for (int off = 32; off; off >>= 1) {
        v += __shfl_down(v, off);
        inc += __shfl_down(inc, off);
    }
    if (s == 0) out[0] = (float)(inc > 0.0 ? v / fmax(inc, 1.0) : 0.0);
}

extern "C" void kernel_launch(void* const* d_in, const int* in_sizes, int n_in,
                              void* d_out, int out_size, void* d_ws, size_t ws_size,
                              hipStream_t stream) {
    const float* pred = (const float*)d_in[0];
    const float* target = (const float*)d_in[1];
    const void* mask = d_in[2];
    float* out = (float*)d_out;

    float* partials = (float*)d_ws;                          // 1920*5 fp32
    float* rpart = partials + (size_t)NBLK * 5;              // 1920 fp32
    unsigned* bitpack = (unsigned*)(rpart + NBLK);           // 1920*320 u32

    const size_t need = (size_t)NBLK * 5 * 4 + (size_t)NBLK * 4 +
                        (size_t)NBLK * BM_DW * 4;
    const bool bitpk = ws_size >= need;

    if (bitpk) {
        sums_kernel<true><<<NBLK, TPB, 0, stream>>>(pred, target, mask,
                                                    partials, bitpack);
        resid_bits_kernel<<<NBLK, TPB, 0, stream>>>(pred, target, partials,
                                                    bitpack, rpart);
    } else {
        sums_kernel<false><<<NBLK, TPB, 0, stream>>>(pred, target, mask,
                                                     partials, bitpack);
        resid_kernel<<<NBLK, TPB, 0, stream>>>(pred, target, mask, partials,
                                               rpart);
    }
    final_kernel<<<1, 64, 0, stream>>>(partials, rpart, out);
}